// Round 1
// baseline (141.601 us; speedup 1.0000x reference)
//
#include <hip/hip_runtime.h>
#include <stdint.h>

#define N_ 32
#define C_ 64
#define T_ 256
#define F_ 64

typedef _Float16 half2_t __attribute__((ext_vector_type(2)));

#define ROWB 528               // 256 f16 = 512 B + 16 B pad (keeps 16B align)
#define SLICEB (C_ * ROWB)     // 33792 B per f-slice
#define XSB (4 * SLICEB)       // 135168 B total staging

#if defined(__has_builtin)
# if __has_builtin(__builtin_amdgcn_fdot2)
#  define HAVE_FDOT2 1
# else
#  define HAVE_FDOT2 0
# endif
#else
# define HAVE_FDOT2 0
#endif

__device__ __forceinline__ uint32_t pack2f16(float a, float b) {
    _Float16 ha = (_Float16)a, hb = (_Float16)b;
    uint32_t lo = (uint32_t)__builtin_bit_cast(uint16_t, ha);
    uint32_t hi = (uint32_t)__builtin_bit_cast(uint16_t, hb);
    return lo | (hi << 16);
}

__device__ __forceinline__ float dot2acc(uint32_t a, uint32_t b, float c) {
#if HAVE_FDOT2
    return __builtin_amdgcn_fdot2(__builtin_bit_cast(half2_t, a),
                                  __builtin_bit_cast(half2_t, b), c, false);
#else
    half2_t ha = __builtin_bit_cast(half2_t, a);
    half2_t hb = __builtin_bit_cast(half2_t, b);
    return c + (float)ha[0] * (float)hb[0] + (float)ha[1] * (float)hb[1];
#endif
}

__global__ __launch_bounds__(256, 1)
void gfc_main(const float* __restrict__ X, const float* __restrict__ gp,
              float* __restrict__ out) {
    __shared__ __align__(16) unsigned char XS[XSB];
    __shared__ float Rbuf[4][C_];

    // XCD-aware swizzle: the 4 f-quad blocks of one (n, 16-f line group)
    // land on the same XCD (assuming bid%8 round-robin) for L2 line reuse.
    int j = blockIdx.x;
    int xcd = j & 7, s = j >> 3;
    int gi = s >> 2, fq4 = s & 3;
    int g = gi * 8 + xcd;            // 0..127 = (n, f16 group)
    int n = g >> 2, f16g = g & 3;
    int f0 = f16g * 16 + fq4 * 4;    // this block's 4 f's

    int tid = threadIdx.x;
    int w = tid >> 6, lane = tid & 63;
    int ci = lane >> 3, ki = lane & 7;

    // ---- stage X[n, :, :, f0:f0+4] -> 4 f16 LDS slices (XOR-swizzled) ----
    const float* Xn = X + (size_t)n * (C_ * T_ * F_) + f0;
    #pragma unroll 4
    for (int it = 0; it < 32; ++it) {
        int item = it * 256 + tid;   // (c, t-pair) work item
        int tp = item & 127;
        int c  = item >> 7;
        const float* p = Xn + (size_t)(c * T_ + 2 * tp) * F_;
        float4 v0 = *(const float4*)p;          // t = 2*tp
        float4 v1 = *(const float4*)(p + F_);   // t = 2*tp+1
        int o = c * ROWB + ((4 * tp) ^ (((c >> 3) & 7) << 4));
        *(uint32_t*)(XS + 0 * SLICEB + o) = pack2f16(v0.x, v1.x);
        *(uint32_t*)(XS + 1 * SLICEB + o) = pack2f16(v0.y, v1.y);
        *(uint32_t*)(XS + 2 * SLICEB + o) = pack2f16(v0.z, v1.z);
        *(uint32_t*)(XS + 3 * SLICEB + o) = pack2f16(v0.w, v1.w);
    }
    __syncthreads();

    // ---- Gram: wave w handles f = f0 + w; lane owns 8x8 (c,k) tile ----
    float acc[8][8];
    #pragma unroll
    for (int a = 0; a < 8; ++a)
        #pragma unroll
        for (int b = 0; b < 8; ++b) acc[a][b] = 0.0f;

    const unsigned char* bp = XS + w * SLICEB;
    for (int tq = 0; tq < 32; ++tq) {           // 8 f16 time samples per iter
        int tb = tq * 16;
        uint4 ca[8], kb[8];
        #pragma unroll
        for (int r = 0; r < 8; ++r) {
            ca[r] = *(const uint4*)(bp + (ci * 8 + r) * ROWB + (tb ^ (ci << 4)));
            kb[r] = *(const uint4*)(bp + (ki * 8 + r) * ROWB + (tb ^ (ki << 4)));
        }
        #pragma unroll
        for (int a = 0; a < 8; ++a)
            #pragma unroll
            for (int b = 0; b < 8; ++b) {
                float t = acc[a][b];
                t = dot2acc(ca[a].x, kb[b].x, t);
                t = dot2acc(ca[a].y, kb[b].y, t);
                t = dot2acc(ca[a].z, kb[b].z, t);
                t = dot2acc(ca[a].w, kb[b].w, t);
                acc[a][b] = t;
            }
    }

    // ---- R = diag(G) via LDS broadcast ----
    if (ci == ki) {
        #pragma unroll
        for (int a = 0; a < 8; ++a) Rbuf[w][ci * 8 + a] = acc[a][a];
    }
    __syncthreads();

    float r1[8], r2[8];
    #pragma unroll
    for (int a = 0; a < 8; ++a) {
        r1[a] = Rbuf[w][ci * 8 + a];
        r2[a] = Rbuf[w][ki * 8 + a];
    }

    // D[c][k] = R[c] + R[k] - 2 G[c][k]  (diagonal exactly 0)
    float d[8][8];
    #pragma unroll
    for (int a = 0; a < 8; ++a)
        #pragma unroll
        for (int b = 0; b < 8; ++b)
            d[a][b] = r1[a] + r2[b] - 2.0f * acc[a][b];

    // mask: strict upper triangle of the full 64x64 (2016 entries), rest=+INF
    bool up = ci < ki, diag = ci == ki;
    float dm[64];
    #pragma unroll
    for (int a = 0; a < 8; ++a)
        #pragma unroll
        for (int b = 0; b < 8; ++b) {
            bool in = up || (diag && (a < b));
            dm[a * 8 + b] = in ? d[a][b] : __builtin_inff();
        }

    // exact rank-1008 (0-based) select: greedy bit-build over positive-float
    // bit space; predicate count(v < u) <= 1008 is monotone in u.
    uint32_t u = 0;
    for (int bit = 30; bit >= 0; --bit) {
        uint32_t cand = u | (1u << bit);
        float piv = __builtin_bit_cast(float, cand);
        int cnt = 0;
        #pragma unroll
        for (int i = 0; i < 64; ++i) cnt += (dm[i] < piv) ? 1 : 0;
        #pragma unroll
        for (int off = 32; off; off >>= 1) cnt += __shfl_xor(cnt, off, 64);
        if (cnt <= 1008) u = cand;
    }

    float sigma2 = __builtin_bit_cast(float, u);       // median of D = sigma^2
    float p10 = exp2f(gp[0] * 3.3219280948873623f);    // 10^gammad
    float ninv = -1.0f / (2.0f * p10 * sigma2);

    // A = exp(-D/denom), coalesced float4 stores
    float* op = out + (size_t)(n * F_ + f0 + w) * 4096 + (ci * 8) * 64 + ki * 8;
    #pragma unroll
    for (int a = 0; a < 8; ++a) {
        float4 lo, hi;
        lo.x = __expf(d[a][0] * ninv); lo.y = __expf(d[a][1] * ninv);
        lo.z = __expf(d[a][2] * ninv); lo.w = __expf(d[a][3] * ninv);
        hi.x = __expf(d[a][4] * ninv); hi.y = __expf(d[a][5] * ninv);
        hi.z = __expf(d[a][6] * ninv); hi.w = __expf(d[a][7] * ninv);
        *(float4*)(op + a * 64) = lo;
        *(float4*)(op + a * 64 + 4) = hi;
    }
}

extern "C" void kernel_launch(void* const* d_in, const int* in_sizes, int n_in,
                              void* d_out, int out_size, void* d_ws, size_t ws_size,
                              hipStream_t stream) {
    (void)in_sizes; (void)n_in; (void)out_size; (void)d_ws; (void)ws_size;
    const float* X  = (const float*)d_in[0];
    const float* gp = (const float*)d_in[1];
    float* out = (float*)d_out;
    gfc_main<<<512, 256, 0, stream>>>(X, gp, out);
}

// Round 2
// 79.462 us; speedup vs baseline: 1.7820x; 1.7820x over previous
//
#include <hip/hip_runtime.h>
#include <stdint.h>

#define SLICEB 32768   // one f-slice: 64 rows x 512 B (256 f16 t-values)

typedef _Float16 f16x8 __attribute__((ext_vector_type(8)));
typedef float f32x4 __attribute__((ext_vector_type(4)));

__device__ __forceinline__ uint32_t pack2(float a, float b) {
    union { _Float16 h[2]; uint32_t u; } p;
    p.h[0] = (_Float16)a; p.h[1] = (_Float16)b;
    return p.u;
}

__global__ __launch_bounds__(512, 2)
void gfc_main(const float* __restrict__ X, const float* __restrict__ gp,
              float* __restrict__ out) {
    __shared__ __align__(16) unsigned char XS[4 * SLICEB];   // 128 KB
    __shared__ float Rbuf[4][64];

    // XCD swizzle: 4 sibling f-quads of one 16-f line group share an XCD L2
    int j = blockIdx.x;
    int xcd = j & 7, s = j >> 3;
    int gi = s >> 2, fq4 = s & 3;
    int g = gi * 8 + xcd;
    int n = g >> 2, f16g = g & 3;
    int f0 = f16g * 16 + fq4 * 4;

    int tid = threadIdx.x;
    int wid = tid >> 6, lane = tid & 63;
    int w4 = wid & 3, hi = wid >> 2;        // f index within quad; wave-pair half
    int l4 = lane & 15, lg = lane >> 4;

    // ---- stage X[n, :, :, f0:f0+4] -> 4 f16 slices, chunk-XOR swizzled ----
    const float* Xn = X + (size_t)n * (64 * 256 * 64) + f0;
    #pragma unroll 4
    for (int it = 0; it < 16; ++it) {
        int item = it * 512 + tid;
        int tp = item & 127, c = item >> 7;
        const float* p = Xn + (size_t)(c * 256 + 2 * tp) * 64;
        float4 v0 = *(const float4*)p;          // t = 2tp
        float4 v1 = *(const float4*)(p + 64);   // t = 2tp+1
        int o = c * 512 + ((tp * 4) ^ ((c & 15) << 4));
        *(uint32_t*)(XS + 0 * SLICEB + o) = pack2(v0.x, v1.x);
        *(uint32_t*)(XS + 1 * SLICEB + o) = pack2(v0.y, v1.y);
        *(uint32_t*)(XS + 2 * SLICEB + o) = pack2(v0.z, v1.z);
        *(uint32_t*)(XS + 3 * SLICEB + o) = pack2(v0.w, v1.w);
    }
    __syncthreads();   // B1

    // ---- Gram via MFMA: wave-pair (w4, w4+4) splits the 10 upper tiles ----
    // lo tiles: (0,0)(0,1)(0,2)(1,1)(1,2)   hi tiles: (2,2)(2,3)(3,3)(0,3)(1,3)
    const unsigned char* bp = XS + w4 * SLICEB;
    f32x4 acc[5] = {f32x4{0,0,0,0}, f32x4{0,0,0,0}, f32x4{0,0,0,0},
                    f32x4{0,0,0,0}, f32x4{0,0,0,0}};
    int rsw = l4 << 4;
    #pragma unroll
    for (int ks = 0; ks < 8; ++ks) {
        f16x8 fr[4];
        #pragma unroll
        for (int i = 0; i < 4; ++i) {
            int row = i * 16 + l4;
            fr[i] = *(const f16x8*)(bp + row * 512 + ((ks * 64 + lg * 16) ^ rsw));
        }
        if (!hi) {
            acc[0] = __builtin_amdgcn_mfma_f32_16x16x32_f16(fr[0], fr[0], acc[0], 0, 0, 0);
            acc[1] = __builtin_amdgcn_mfma_f32_16x16x32_f16(fr[0], fr[1], acc[1], 0, 0, 0);
            acc[2] = __builtin_amdgcn_mfma_f32_16x16x32_f16(fr[0], fr[2], acc[2], 0, 0, 0);
            acc[3] = __builtin_amdgcn_mfma_f32_16x16x32_f16(fr[1], fr[1], acc[3], 0, 0, 0);
            acc[4] = __builtin_amdgcn_mfma_f32_16x16x32_f16(fr[1], fr[2], acc[4], 0, 0, 0);
        } else {
            acc[0] = __builtin_amdgcn_mfma_f32_16x16x32_f16(fr[2], fr[2], acc[0], 0, 0, 0);
            acc[1] = __builtin_amdgcn_mfma_f32_16x16x32_f16(fr[2], fr[3], acc[1], 0, 0, 0);
            acc[2] = __builtin_amdgcn_mfma_f32_16x16x32_f16(fr[3], fr[3], acc[2], 0, 0, 0);
            acc[3] = __builtin_amdgcn_mfma_f32_16x16x32_f16(fr[0], fr[3], acc[3], 0, 0, 0);
            acc[4] = __builtin_amdgcn_mfma_f32_16x16x32_f16(fr[1], fr[3], acc[4], 0, 0, 0);
        }
    }

    // ---- R = diag(G): C/D layout col=l4, row=lg*4+reg (m89-verified) ----
    #pragma unroll
    for (int reg = 0; reg < 4; ++reg) {
        if (lg * 4 + reg == l4) {
            if (!hi) {
                Rbuf[w4][0 * 16 + l4] = acc[0][reg];   // tile (0,0)
                Rbuf[w4][1 * 16 + l4] = acc[3][reg];   // tile (1,1)
            } else {
                Rbuf[w4][2 * 16 + l4] = acc[0][reg];   // tile (2,2)
                Rbuf[w4][3 * 16 + l4] = acc[2][reg];   // tile (3,3)
            }
        }
    }
    __syncthreads();   // B2: Rbuf ready; all XS gram reads done

    // ---- D = R_r + R_c - 2G for held tiles; f16-bit keys for median ----
    const int TI_lo[5] = {0, 0, 0, 1, 1}, TJ_lo[5] = {0, 1, 2, 1, 2};
    const int TI_hi[5] = {2, 2, 3, 0, 1}, TJ_hi[5] = {2, 3, 3, 3, 3};
    float dm[5][4];
    int keys[40];
    const float* Rw = Rbuf[w4];
    #pragma unroll
    for (int t = 0; t < 5; ++t) {
        int ti = hi ? TI_hi[t] : TI_lo[t];
        int tj = hi ? TJ_hi[t] : TJ_lo[t];
        int col = tj * 16 + l4;
        float Rc = Rw[col];
        #pragma unroll
        for (int reg = 0; reg < 4; ++reg) {
            int row = ti * 16 + lg * 4 + reg;
            float v = Rw[row] + Rc - 2.0f * acc[t][reg];
            dm[t][reg] = v;
            _Float16 hv = (_Float16)fmaxf(v, 0.0f);
            uint16_t kb = __builtin_bit_cast(uint16_t, hv);
            keys[t * 4 + reg] = (row < col) ? (int)kb : 0x7FFF;
        }
    }

    // ---- one-shot key exchange between wave-pair halves (reuses XS) ----
    uint32_t* exch = (uint32_t*)(XS + w4 * SLICEB);
    uint32_t* mywr = exch + (hi ? 1280 : 0);
    #pragma unroll
    for (int e = 0; e < 20; ++e) mywr[e * 64 + lane] = (uint32_t)keys[e];
    __syncthreads();   // B3
    const uint32_t* prd = exch + (hi ? 0 : 1280);
    #pragma unroll
    for (int e = 0; e < 20; ++e) keys[20 + e] = (int)prd[e * 64 + lane];

    // ---- exact rank-1008 select on 15-bit f16 keys (both halves, redundant) ----
    int u = 0;
    for (int bit = 14; bit >= 0; --bit) {
        int cand = u | (1 << bit);
        int cnt = 0;
        #pragma unroll
        for (int i = 0; i < 40; ++i) cnt += (keys[i] < cand) ? 1 : 0;
        #pragma unroll
        for (int off = 32; off; off >>= 1) cnt += __shfl_xor(cnt, off, 64);
        if (cnt <= 1008) u = cand;
    }
    float sigma2 = (float)__builtin_bit_cast(_Float16, (uint16_t)u);
    float p10 = exp2f(gp[0] * 3.3219280948873623f);   // 10^gammad
    float ninv = -1.0f / (2.0f * p10 * sigma2);

    // ---- fill swizzled D tile (direct + symmetric mirror), then exp+store ----
    unsigned char* Dm = XS + w4 * SLICEB + 16384;
    #pragma unroll
    for (int t = 0; t < 5; ++t) {
        int ti = hi ? TI_hi[t] : TI_lo[t];
        int tj = hi ? TJ_hi[t] : TJ_lo[t];
        int col = tj * 16 + l4;
        #pragma unroll
        for (int reg = 0; reg < 4; ++reg) {
            int row = ti * 16 + lg * 4 + reg;
            float v = dm[t][reg];
            *(float*)(Dm + row * 256 + ((col * 4) ^ ((row & 15) << 4))) = v;
            if (ti != tj)
                *(float*)(Dm + col * 256 + ((row * 4) ^ ((col & 15) << 4))) = v;
        }
    }
    __syncthreads();   // B4

    float* op = out + (size_t)(n * 64 + f0 + w4) * 4096;
    int rbase = hi * 32;
    #pragma unroll
    for (int ps = 0; ps < 8; ++ps) {
        int row = rbase + ps * 4 + lg;
        f32x4 v = *(const f32x4*)(Dm + row * 256 + ((l4 * 16) ^ ((row & 15) << 4)));
        float4 r;
        r.x = __expf(v[0] * ninv);
        r.y = __expf(v[1] * ninv);
        r.z = __expf(v[2] * ninv);
        r.w = __expf(v[3] * ninv);
        *(float4*)(op + row * 64 + l4 * 4) = r;
    }
}

extern "C" void kernel_launch(void* const* d_in, const int* in_sizes, int n_in,
                              void* d_out, int out_size, void* d_ws, size_t ws_size,
                              hipStream_t stream) {
    (void)in_sizes; (void)n_in; (void)out_size; (void)d_ws; (void)ws_size;
    const float* X  = (const float*)d_in[0];
    const float* gp = (const float*)d_in[1];
    float* out = (float*)d_out;
    gfc_main<<<512, 512, 0, stream>>>(X, gp, out);
}

// Round 4
// 63.169 us; speedup vs baseline: 2.2416x; 1.2579x over previous
//
#include <hip/hip_runtime.h>
#include <stdint.h>

typedef _Float16 f16x8 __attribute__((ext_vector_type(8)));
typedef float f32x4 __attribute__((ext_vector_type(4)));

__device__ __forceinline__ uint32_t pack2(float a, float b) {
    union { _Float16 h[2]; uint32_t u; } p;
    p.h[0] = (_Float16)a; p.h[1] = (_Float16)b;
    return p.u;
}

__device__ __forceinline__ f32x4 MF(f16x8 a, f16x8 b, f32x4 c) {
    return __builtin_amdgcn_mfma_f32_16x16x32_f16(a, b, c, 0, 0, 0);
}

__global__ __launch_bounds__(512, 4)
void gfc_main(const float* __restrict__ X, const float* __restrict__ gp,
              float* __restrict__ out) {
    // 64 KB: 4 f-slices x (64 c-rows x 256 B) -- one 128-t chunk, f16, swizzled
    __shared__ __align__(16) unsigned char XS[65536];
    __shared__ uint32_t histc[4][256];   // coarse: f16-key bits >> 7
    __shared__ uint32_t histf[4][128];   // fine:   f16-key bits & 127
    __shared__ float Rbuf[4][64];

    // XCD swizzle: 4 sibling f-quads of one (n, 16-f line group) share an XCD
    int j = blockIdx.x;
    int xcd = j & 7, s = j >> 3;
    int gi = s >> 2, fq4 = s & 3;
    int g = gi * 8 + xcd;
    int n = g >> 2, f16g = g & 3;
    int f0 = f16g * 16 + fq4 * 4;

    int tid = threadIdx.x;
    int wid = tid >> 6, lane = tid & 63;
    int w4 = wid & 3, hi = wid >> 2;     // f within quad; row-half of C
    int l4 = lane & 15, lg = lane >> 4;

    float p10 = exp2f(gp[0] * 3.3219280948873623f);   // 10^gammad

    // zero histograms (atomics happen much later; one barrier covers)
    {
        uint32_t* hz = &histc[0][0];
        hz[tid] = 0; hz[512 + tid] = 0;
        (&histf[0][0])[tid] = 0;
    }

    const float* Xn = X + (size_t)n * 1048576 + f0;

    f32x4 dd[2][4];
    #pragma unroll
    for (int a = 0; a < 2; ++a)
        #pragma unroll
        for (int b = 0; b < 4; ++b) dd[a][b] = f32x4{0, 0, 0, 0};

    #pragma unroll
    for (int ch = 0; ch < 2; ++ch) {
        if (ch) __syncthreads();            // chunk0 reads done before overwrite
        const float* Xc = Xn + ch * 8192;   // t base = ch*128
        #pragma unroll
        for (int bt = 0; bt < 2; ++bt) {
            float4 v[4][2];
            #pragma unroll
            for (int i = 0; i < 4; ++i) {   // 8 loads in flight
                int c = (bt * 4 + i) * 8 + wid;
                const float* p = Xc + (size_t)c * 16384 + lane * 128;
                v[i][0] = *(const float4*)p;         // t = 2*lane
                v[i][1] = *(const float4*)(p + 64);  // t = 2*lane+1
            }
            #pragma unroll
            for (int i = 0; i < 4; ++i) {
                int c = (bt * 4 + i) * 8 + wid;
                int o = c * 256 + ((lane * 4) ^ ((c & 7) << 4));
                *(uint32_t*)(XS + o)         = pack2(v[i][0].x, v[i][1].x);
                *(uint32_t*)(XS + 16384 + o) = pack2(v[i][0].y, v[i][1].y);
                *(uint32_t*)(XS + 32768 + o) = pack2(v[i][0].z, v[i][1].z);
                *(uint32_t*)(XS + 49152 + o) = pack2(v[i][0].w, v[i][1].w);
            }
        }
        __syncthreads();

        // Gram, 8 tiles/wave: rows (2hi,2hi+1)x16, all 4 col-tiles.
        // mfma(fr[tj], fr[ti]) -> lane holds G[ti*16+l4][tj*16+lg*4+reg]
        const unsigned char* bp = XS + w4 * 16384;
        #pragma unroll
        for (int ks = 0; ks < 4; ++ks) {
            f16x8 fr[4];
            #pragma unroll
            for (int i2 = 0; i2 < 4; ++i2)
                fr[i2] = *(const f16x8*)(bp + (i2 * 16 + l4) * 256 +
                                         ((ks * 64 + lg * 16) ^ ((l4 & 7) << 4)));
            if (!hi) {
                #pragma unroll
                for (int tj = 0; tj < 4; ++tj) {
                    dd[0][tj] = MF(fr[tj], fr[0], dd[0][tj]);
                    dd[1][tj] = MF(fr[tj], fr[1], dd[1][tj]);
                }
            } else {
                #pragma unroll
                for (int tj = 0; tj < 4; ++tj) {
                    dd[0][tj] = MF(fr[tj], fr[2], dd[0][tj]);
                    dd[1][tj] = MF(fr[tj], fr[3], dd[1][tj]);
                }
            }
        }
    }

    // R = diag(G). Diag tiles: dd[0][2hi], dd[1][2hi+1]; elem where lg*4+reg==l4
    {
        f32x4 dg0 = hi ? dd[0][2] : dd[0][0];
        f32x4 dg1 = hi ? dd[1][3] : dd[1][1];
        if (lg == (l4 >> 2)) {
            int r = l4 & 3;
            float v0 = r == 0 ? dg0[0] : r == 1 ? dg0[1] : r == 2 ? dg0[2] : dg0[3];
            float v1 = r == 0 ? dg1[0] : r == 1 ? dg1[1] : r == 2 ? dg1[2] : dg1[3];
            Rbuf[w4][(hi * 2) * 16 + l4] = v0;
            Rbuf[w4][(hi * 2 + 1) * 16 + l4] = v1;
        }
    }
    __syncthreads();

    // D = R_row + R_col - 2G, in place (diag exactly 0)
    float Rr0 = Rbuf[w4][(hi * 2) * 16 + l4];
    float Rr1 = Rbuf[w4][(hi * 2 + 1) * 16 + l4];
    #pragma unroll
    for (int tj = 0; tj < 4; ++tj) {
        f32x4 Rc = *(const f32x4*)&Rbuf[w4][tj * 16 + lg * 4];
        #pragma unroll
        for (int r = 0; r < 4; ++r) {
            dd[0][tj][r] = Rr0 + Rc[r] - 2.0f * dd[0][tj][r];
            dd[1][tj][r] = Rr1 + Rc[r] - 2.0f * dd[1][tj][r];
        }
    }

    // coarse histogram of f16 keys (strict upper triangle only)
    uint32_t* hc = histc[w4];
    #pragma unroll
    for (int tt = 0; tt < 2; ++tt) {
        int row = (hi * 2 + tt) * 16 + l4;
        #pragma unroll
        for (int tj = 0; tj < 4; ++tj)
            #pragma unroll
            for (int r = 0; r < 4; ++r) {
                int col = tj * 16 + lg * 4 + r;
                if (row < col) {
                    _Float16 hx = (_Float16)fmaxf(dd[tt][tj][r], 0.0f);
                    uint32_t kb = (uint32_t)__builtin_bit_cast(uint16_t, hx);
                    atomicAdd(&hc[kb >> 7], 1u);
                }
            }
    }
    __syncthreads();

    // coarse scan: smallest bin B with cum >= 1009 (rank 1008, 0-based)
    int B, tf;
    {
        uint4 hh = *(const uint4*)&hc[lane * 4];
        int sB = (int)(hh.x + hh.y + hh.z + hh.w);
        int incl = sB;
        #pragma unroll
        for (int off = 1; off < 64; off <<= 1) {
            int t = __shfl_up(incl, off, 64);
            if (lane >= off) incl += t;
        }
        unsigned long long bal = __ballot(incl >= 1009);
        int L = __ffsll(bal) - 1;
        int inclL = __shfl(incl, L, 64);
        int a0 = __shfl((int)hh.x, L, 64);
        int a1 = __shfl((int)hh.y, L, 64);
        int a2 = __shfl((int)hh.z, L, 64);
        int a3 = __shfl((int)hh.w, L, 64);
        int excl = inclL - (a0 + a1 + a2 + a3);
        int cum;
        if (excl + a0 >= 1009)                { B = L * 4;     cum = excl; }
        else if (excl + a0 + a1 >= 1009)      { B = L * 4 + 1; cum = excl + a0; }
        else if (excl + a0 + a1 + a2 >= 1009) { B = L * 4 + 2; cum = excl + a0 + a1; }
        else                                  { B = L * 4 + 3; cum = excl + a0 + a1 + a2; }
        tf = 1009 - cum;
    }

    // fine histogram within bin B
    uint32_t* hf = histf[w4];
    #pragma unroll
    for (int tt = 0; tt < 2; ++tt) {
        int row = (hi * 2 + tt) * 16 + l4;
        #pragma unroll
        for (int tj = 0; tj < 4; ++tj)
            #pragma unroll
            for (int r = 0; r < 4; ++r) {
                int col = tj * 16 + lg * 4 + r;
                if (row < col) {
                    _Float16 hx = (_Float16)fmaxf(dd[tt][tj][r], 0.0f);
                    uint32_t kb = (uint32_t)__builtin_bit_cast(uint16_t, hx);
                    if ((int)(kb >> 7) == B) atomicAdd(&hf[kb & 127], 1u);
                }
            }
    }
    __syncthreads();

    float sigma2;
    {
        uint2 gg = *(const uint2*)&hf[lane * 2];
        int s2 = (int)(gg.x + gg.y);
        int incl = s2;
        #pragma unroll
        for (int off = 1; off < 64; off <<= 1) {
            int t = __shfl_up(incl, off, 64);
            if (lane >= off) incl += t;
        }
        unsigned long long bal = __ballot(incl >= tf);
        int L2 = __ffsll(bal) - 1;
        int inclL = __shfl(incl, L2, 64);
        int b0 = __shfl((int)gg.x, L2, 64);
        int b1 = __shfl((int)gg.y, L2, 64);
        int excl = inclL - (b0 + b1);
        int F = (excl + b0 >= tf) ? L2 * 2 : L2 * 2 + 1;
        uint16_t v15 = (uint16_t)((B << 7) | F);
        sigma2 = (float)__builtin_bit_cast(_Float16, v15);
    }
    float ninv = -1.0f / (2.0f * p10 * sigma2);

    // epilogue: A = exp(-D/denom); lane holds 4 consecutive cols -> float4 store
    float* op = out + ((size_t)(n * 64 + f0 + w4) << 12);
    #pragma unroll
    for (int tt = 0; tt < 2; ++tt) {
        int row = (hi * 2 + tt) * 16 + l4;
        #pragma unroll
        for (int tj = 0; tj < 4; ++tj) {
            float4 rv;
            rv.x = __expf(dd[tt][tj][0] * ninv);
            rv.y = __expf(dd[tt][tj][1] * ninv);
            rv.z = __expf(dd[tt][tj][2] * ninv);
            rv.w = __expf(dd[tt][tj][3] * ninv);
            *(float4*)(op + row * 64 + tj * 16 + lg * 4) = rv;
        }
    }
}

extern "C" void kernel_launch(void* const* d_in, const int* in_sizes, int n_in,
                              void* d_out, int out_size, void* d_ws, size_t ws_size,
                              hipStream_t stream) {
    (void)in_sizes; (void)n_in; (void)out_size; (void)d_ws; (void)ws_size;
    const float* X  = (const float*)d_in[0];
    const float* gp = (const float*)d_in[1];
    float* out = (float*)d_out;
    gfc_main<<<512, 512, 0, stream>>>(X, gp, out);
}